// Round 21
// baseline (180.542 us; speedup 1.0000x reference)
//
#include <hip/hip_runtime.h>

// SplatAwareFeedForward on MI355X (gfx950).
// Pipeline: route -> prep (weight transposes ONLY) ->
//           G1 (fused gather+cast f32 x, 64x64 tiles, XCD-colocated siblings; r19-proven) ->
//           G2 (m97-style, XCD-colocated linear grid) ->
//           dense GEMM3/GEMM4 (m97 128x128, XCD swizzle).
// r20 lesson: async-f32 staging for G1 regressed (cvt VALU + bank conflicts, same
// 68 MB); G1 is latency-floored at ~56 us across 3 structures -> keep r19 form.
// This round: G2's dim3(8,144) grid scattered the 8 ntile-siblings of each row-tile
// across 8 XCDs (r18 bug class) -> linear grid, siblings differ by 8 -> same XCD.
// Workspace layout (bytes):
//   gbuf  @ 0        : 33,554,432  (dense g-buffer GEMM3 out / GEMM4 in)
//   w1t   @ 33554432 :  8,388,608  (E*[H][D] bf16, transposed W1)
//   w2t   @ 41943040 :  8,388,608  (E*[D][H] bf16, transposed W2)
//   wg1t  @ 50331648 :  2,097,152  ([D][D] bf16, transposed Wg1)
//   wg2t  @ 52428800 :  2,097,152  ([D][D] bf16, transposed Wg2)
//   hbuf  @ 54525952 :  8,388,608  (B*S*H bf16, expert-sorted hidden)
//   rout  @ 62914560 : 33,554,432  (B*S*D bf16, routed output, natural order)
//   offs  @ 96468992 : 68          (E+1 ints)
//   order @ 96469248 : 16,384      (S ints sorted by expert)
//   tileE @ 96485632 : 576         (expert id per 128-row tile, <=144)
//   tileR @ 96486208 : 576         (sorted-row start per 128-row tile)
//   ntl   @ 96486784 : 4           (128-row tile count)
//   t64E  @ 96487424 : 1,152       (expert id per 64-row tile, <=272)
//   t64R  @ 96488704 : 1,152       (sorted-row start per 64-row tile)
//   ntl64 @ 96489984 : 4           (64-row tile count)

#define DEV __device__ __forceinline__

typedef float f32x4 __attribute__((ext_vector_type(4)));
typedef short short8 __attribute__((ext_vector_type(8)));

DEV unsigned short f2bf(float f) {
  unsigned u = __float_as_uint(f);
  u += 0x7fffu + ((u >> 16) & 1u);   // round-to-nearest-even
  return (unsigned short)(u >> 16);
}

DEV void gload16(const void* g, void* l) {
  __builtin_amdgcn_global_load_lds(
      (const __attribute__((address_space(1))) unsigned int*)g,
      (__attribute__((address_space(3))) unsigned int*)l, 16, 0, 0);
}

DEV float gelu_exact(float v) {
  return 0.5f * v * (1.0f + erff(v * 0.70710678118654752f));
}

// ---------------- routing: sorted order + 128-row and 64-row tile lists ----------------
__global__ __launch_bounds__(256) void route_kernel(
    const int* __restrict__ sid, int S, int* __restrict__ offs, int* __restrict__ order,
    int* __restrict__ tileE, int* __restrict__ tileR, int* __restrict__ ntl,
    int* __restrict__ t64E, int* __restrict__ t64R, int* __restrict__ ntl64) {
  __shared__ int cnt[16], cur[16];
  const int t = threadIdx.x;
  if (t < 16) cnt[t] = 0;
  __syncthreads();
  for (int s = t; s < S; s += 256) atomicAdd(&cnt[sid[s]], 1);
  __syncthreads();
  if (t == 0) {
    int a = 0;
    for (int e = 0; e < 16; e++) { offs[e] = a; cur[e] = a; a += cnt[e]; }
    offs[16] = a;
    int nt = 0, n64 = 0;
    for (int e = 0; e < 16; e++) {
      const int rows = 4 * cnt[e];
      for (int r = 0; r < rows; r += 128) {
        tileE[nt] = e; tileR[nt] = 4 * offs[e] + r; nt++;
      }
      for (int r = 0; r < rows; r += 64) {
        t64E[n64] = e; t64R[n64] = 4 * offs[e] + r; n64++;
      }
    }
    ntl[0] = nt;
    ntl64[0] = n64;
  }
  __syncthreads();
  for (int s = t; s < S; s += 256) {
    int p = atomicAdd(&cur[sid[s]], 1);
    order[p] = s;
  }
}

// ---------------- prep: weight transpose-casts ONLY ----------------
__global__ __launch_bounds__(256) void prep_kernel(
    const float* __restrict__ W1, unsigned short* __restrict__ w1t,
    const float* __restrict__ W2, unsigned short* __restrict__ w2t,
    const float* __restrict__ Wg1, unsigned short* __restrict__ wg1t,
    const float* __restrict__ Wg2, unsigned short* __restrict__ wg2t) {
  __shared__ float tile[64][65];
  const int t = threadIdx.x;
  int id = (int)blockIdx.x;
  const float* in; unsigned short* out;
  int R, C, r0, c0; long base;
  if (id < 1024) {          // W1: [1024][256] -> [256][1024] per expert
    in = W1; out = w1t; R = 1024; C = 256;
    base = (long)(id >> 6) * 262144;
    r0 = ((id >> 2) & 15) * 64; c0 = (id & 3) * 64;
  } else if (id < 2048) {   // W2: [256][1024] -> [1024][256] per expert
    id -= 1024;
    in = W2; out = w2t; R = 256; C = 1024;
    base = (long)(id >> 6) * 262144;
    r0 = ((id >> 4) & 3) * 64; c0 = (id & 15) * 64;
  } else if (id < 2304) {   // Wg1
    id -= 2048;
    in = Wg1; out = wg1t; R = 1024; C = 1024; base = 0;
    r0 = (id >> 4) * 64; c0 = (id & 15) * 64;
  } else {                  // Wg2
    id -= 2304;
    in = Wg2; out = wg2t; R = 1024; C = 1024; base = 0;
    r0 = (id >> 4) * 64; c0 = (id & 15) * 64;
  }
  const int cc = t & 63, rr = t >> 6;
#pragma unroll
  for (int i = 0; i < 16; i++) {
    int r = rr + i * 4;
    tile[r][cc] = in[base + (long)(r0 + r) * C + (c0 + cc)];
  }
  __syncthreads();
#pragma unroll
  for (int i = 0; i < 16; i++) {
    int c = rr + i * 4;
    out[base + (long)(c0 + c) * R + (r0 + cc)] = f2bf(tile[cc][c]);
  }
}

// ---------------- G1: h = gelu(gather(x,f32) @ W1[e] + b1[e]), 64x64 tiles ----------------
// r19-proven: linear 1088-block grid, XCD-colocated ntile siblings; A gathered f32
// via order[], cast in regs, ds_write swizzled-linear; B via gload16.
__global__ __launch_bounds__(256, 4) void gemm_g1g(
    const float* __restrict__ x,
    const unsigned short* __restrict__ w1t, const float* __restrict__ b1,
    unsigned short* __restrict__ hbuf,
    const int* __restrict__ order, const int* __restrict__ offs,
    const int* __restrict__ t64E, const int* __restrict__ t64R,
    const int* __restrict__ ntl64) {
  constexpr int S = 4096, D = 1024, H = 256;
  const int b = (int)blockIdx.x;
  const int xcd = b & 7;
  const int q = b >> 3;
  const int ntile = q & 3;                 // 0..3 (64-col block of H)
  const int ti = (q >> 2) * 8 + xcd;       // 0..271 (64-row tile)
  if (ti >= ntl64[0]) return;
  const int t = (int)threadIdx.x;
  const int lane = t & 63;
  const int w = t >> 6;
  const int wm = w >> 1, wn = w & 1;       // 2x2 waves, 32x32 each

  const int e = t64E[ti];
  const int rowBase = t64R[ti];
  int Me = 4 * offs[e + 1] - rowBase;
  if (Me > 64) Me = 64;

  __shared__ __align__(16) unsigned short lA[64 * 64];    // 8KB (x tile, bf16, swizzled)
  __shared__ __align__(16) unsigned short lB[64 * 64];    // 8KB (W1 slab)

  const float* xsrc[2];
  int aDst[2];
#pragma unroll
  for (int i = 0; i < 2; i++) {
    const int row = i * 32 + (t >> 3);
    const int koff = (((t & 7) * 16) ^ ((row & 7) << 4)) >> 1;
    const int rr = (row < Me) ? row : (Me - 1);
    const int g = rowBase + rr;
    xsrc[i] = x + ((long)(g & 3) * S + order[g >> 2]) * D + koff;
    aDst[i] = row * 64 + (t & 7) * 8;
  }
  const unsigned short* bSrc[2];
#pragma unroll
  for (int i = 0; i < 2; i++) {
    const int row = i * 32 + (t >> 3);
    bSrc[i] = w1t + (long)e * H * D + (long)(ntile * 64 + row) * D +
              ((((t & 7) * 16) ^ ((row & 7) << 4)) >> 1);
  }
  const int dstE = (t >> 3) * 64 + (t & 7) * 8;

  f32x4 acc[2][2] = {};
  float4 xv[2][2];
#pragma unroll
  for (int i = 0; i < 2; i++) {
    xv[i][0] = *(const float4*)(xsrc[i]);
    xv[i][1] = *(const float4*)(xsrc[i] + 4);
  }

  for (int kt = 0; kt < 16; kt++) {
    __syncthreads();
#pragma unroll
    for (int i = 0; i < 2; i++) {
      short8 av;
      av[0] = (short)f2bf(xv[i][0].x); av[1] = (short)f2bf(xv[i][0].y);
      av[2] = (short)f2bf(xv[i][0].z); av[3] = (short)f2bf(xv[i][0].w);
      av[4] = (short)f2bf(xv[i][1].x); av[5] = (short)f2bf(xv[i][1].y);
      av[6] = (short)f2bf(xv[i][1].z); av[7] = (short)f2bf(xv[i][1].w);
      *(short8*)(lA + aDst[i]) = av;
      gload16(bSrc[i] + (kt << 6), lB + i * 2048 + dstE);
    }
    if (kt < 15) {
#pragma unroll
      for (int i = 0; i < 2; i++) {
        xv[i][0] = *(const float4*)(xsrc[i] + (kt + 1) * 64);
        xv[i][1] = *(const float4*)(xsrc[i] + (kt + 1) * 64 + 4);
      }
    }
    __syncthreads();
#pragma unroll
    for (int kk = 0; kk < 2; kk++) {
      short8 aF[2], bF[2];
      const int kb = kk * 64 + ((lane >> 4) << 4);
#pragma unroll
      for (int mi = 0; mi < 2; mi++) {
        const int row = wm * 32 + mi * 16 + (lane & 15);
        aF[mi] = *(const short8*)((const char*)lA + row * 128 + (kb ^ ((row & 7) << 4)));
      }
#pragma unroll
      for (int ni = 0; ni < 2; ni++) {
        const int row = wn * 32 + ni * 16 + (lane & 15);
        bF[ni] = *(const short8*)((const char*)lB + row * 128 + (kb ^ ((row & 7) << 4)));
      }
#pragma unroll
      for (int mi = 0; mi < 2; mi++)
#pragma unroll
        for (int ni = 0; ni < 2; ni++)
          acc[mi][ni] = __builtin_amdgcn_mfma_f32_16x16x32_bf16(aF[mi], bF[ni], acc[mi][ni], 0, 0, 0);
    }
  }

  float bc[2];
#pragma unroll
  for (int ni = 0; ni < 2; ni++)
    bc[ni] = b1[e * H + ntile * 64 + wn * 32 + ni * 16 + (lane & 15)];
#pragma unroll
  for (int mi = 0; mi < 2; mi++)
#pragma unroll
    for (int j = 0; j < 4; j++) {
      const int lrow = wm * 32 + mi * 16 + ((lane >> 4) << 2) + j;
      if (lrow >= Me) continue;
      const long crow = rowBase + lrow;
#pragma unroll
      for (int ni = 0; ni < 2; ni++) {
        const float v = gelu_exact(acc[mi][ni][j] + bc[ni]);
        hbuf[crow * H + ntile * 64 + wn * 32 + ni * 16 + (lane & 15)] = f2bf(v);
      }
    }
}

// ---------------- G2: expert 128x128x64, linear grid, XCD-colocated ntile siblings ----------------
// 1152 blocks; decode: xcd=b&7, q=b>>3, tileN=q&7, ti=(q>>3)*8+xcd. The 8 tileN-
// siblings of a row-tile differ by 8 in id -> same XCD, adjacent in time -> the
// 64KB hbuf A-panel is read from HBM once and L2-hits for siblings 2..8.
__global__ __launch_bounds__(256, 4) void gemm_g2(
    const unsigned short* __restrict__ A, const unsigned short* __restrict__ BT,
    const float* __restrict__ bias, unsigned short* __restrict__ Cout,
    int N, int K,
    const int* __restrict__ order, const int* __restrict__ offs,
    const int* __restrict__ tileE, const int* __restrict__ tileR,
    const int* __restrict__ ntl,
    int S, long btStride, int biasStride) {
  const int b = (int)blockIdx.x;
  const int xcd = b & 7;
  const int q = b >> 3;
  const int tileN = q & 7;                 // 0..7 (128-col block of D)
  const int ti = (q >> 3) * 8 + xcd;       // 0..143 (128-row tile)
  if (ti >= ntl[0]) return;
  const int t = (int)threadIdx.x;
  const int lane = t & 63;
  const int w = t >> 6;
  const int wm = w >> 1, wn = w & 1;

  const int e = tileE[ti];
  const int rowBase = tileR[ti];
  int Me = 4 * offs[e + 1] - rowBase;
  if (Me > 128) Me = 128;
  const unsigned short* bt = BT + (long)e * btStride;
  const float* bs = bias + (long)e * biasStride;

  __shared__ __align__(16) unsigned short lA[128 * 64];
  __shared__ __align__(16) unsigned short lB[128 * 64];

  const unsigned short* aSrc[4];
  const unsigned short* bSrc[4];
  {
    const int qq = t & 7;
#pragma unroll
    for (int i = 0; i < 4; i++) {
      const int row = i * 32 + (t >> 3);
      const int koff = ((qq * 16) ^ ((row & 7) << 4)) >> 1;
      const int rr = (row < Me) ? row : (Me - 1);
      aSrc[i] = A + (long)(rowBase + rr) * K + koff;
      const int col = tileN * 128 + row;
      bSrc[i] = bt + (long)col * K + koff;
    }
  }

  f32x4 acc[4][4] = {};

  const int KT = K >> 6;
  for (int kt = 0; kt < KT; kt++) {
    __syncthreads();
#pragma unroll
    for (int i = 0; i < 4; i++) {
      gload16(aSrc[i] + (kt << 6), (void*)(lA + i * 2048 + w * 512));
      gload16(bSrc[i] + (kt << 6), (void*)(lB + i * 2048 + w * 512));
    }
    __syncthreads();
#pragma unroll
    for (int kk = 0; kk < 2; kk++) {
      short8 af[4], bfr[4];
      const int kbyte = kk * 64 + (lane >> 4) * 16;
#pragma unroll
      for (int mi = 0; mi < 4; mi++) {
        const int row = wm * 64 + mi * 16 + (lane & 15);
        const int off = row * 128 + (kbyte ^ ((row & 7) << 4));
        af[mi] = *(const short8*)((const char*)lA + off);
      }
#pragma unroll
      for (int ni = 0; ni < 4; ni++) {
        const int row = wn * 64 + ni * 16 + (lane & 15);
        const int off = row * 128 + (kbyte ^ ((row & 7) << 4));
        bfr[ni] = *(const short8*)((const char*)lB + off);
      }
#pragma unroll
      for (int mi = 0; mi < 4; mi++)
#pragma unroll
        for (int ni = 0; ni < 4; ni++)
          acc[mi][ni] = __builtin_amdgcn_mfma_f32_16x16x32_bf16(af[mi], bfr[ni], acc[mi][ni], 0, 0, 0);
    }
  }

  float bcol[4];
#pragma unroll
  for (int ni = 0; ni < 4; ni++)
    bcol[ni] = bs[tileN * 128 + wn * 64 + ni * 16 + (lane & 15)];

#pragma unroll
  for (int mi = 0; mi < 4; mi++) {
#pragma unroll
    for (int j = 0; j < 4; j++) {
      const int lrow = wm * 64 + mi * 16 + ((lane >> 4) * 4) + j;
      if (lrow >= Me) continue;
      const int g = rowBase + lrow;
      const long crow = (long)(g & 3) * S + order[g >> 2];   // scatter to natural rows
#pragma unroll
      for (int ni = 0; ni < 4; ni++) {
        const float v = acc[mi][ni][j] + bcol[ni];
        Cout[crow * (long)N + tileN * 128 + wn * 64 + ni * 16 + (lane & 15)] = f2bf(v);
      }
    }
  }
}

// ---------------- dense 128x128x64 GEMM (m97 structure, 4 blocks/CU, XCD swizzle) ----------------
template <bool GELU, bool OUT_F32>
__global__ __launch_bounds__(256, 4) void gemm_dense128(
    const unsigned short* __restrict__ A, const unsigned short* __restrict__ BT,
    const float* __restrict__ bias, void* __restrict__ Cout,
    int N, int K, int ntiles) {
  const int t = (int)threadIdx.x;
  const int lane = t & 63;
  const int w = t >> 6;
  const int wm = w >> 1, wn = w & 1;

  const int cpx = (int)gridDim.x >> 3;
  const int swz = ((int)blockIdx.x & 7) * cpx + ((int)blockIdx.x >> 3);
  const int mtile = swz / ntiles, ntile = swz % ntiles;

  __shared__ __align__(16) unsigned short lA[128 * 64];
  __shared__ __align__(16) unsigned short lB[128 * 64];

  const unsigned short* aSrc[4];
  const unsigned short* bSrc[4];
  {
    const int q = t & 7;
#pragma unroll
    for (int i = 0; i < 4; i++) {
      const int row = i * 32 + (t >> 3);
      const int koff = ((q * 16) ^ ((row & 7) << 4)) >> 1;
      aSrc[i] = A + (long)(mtile * 128 + row) * K + koff;
      bSrc[i] = BT + (long)(ntile * 128 + row) * K + koff;
    }
  }

  f32x4 acc[4][4] = {};

  const int KT = K >> 6;
  for (int kt = 0; kt < KT; kt++) {
    __syncthreads();
#pragma unroll
    for (int i = 0; i < 4; i++) {
      gload16(aSrc[i] + (kt << 6), (void*)(lA + i * 2048 + w * 512));
      gload16(bSrc[i] + (kt << 6), (void*)(lB + i * 2048 + w * 512));
    }
    __syncthreads();
#pragma unroll
    for (int kk = 0; kk < 2; kk++) {
      short8 af[4], bfr[4];
      const int kbyte = kk * 64 + (lane >> 4) * 16;
#pragma unroll
      for (int mi = 0; mi < 4; mi++) {
        const int row = wm * 64 + mi * 16 + (lane & 15);
        const int off = row * 128 + (kbyte ^ ((row & 7) << 4));
        af[mi] = *(const short8*)((const char*)lA + off);
      }
#pragma unroll
      for (int ni = 0; ni < 4; ni++) {
        const int row = wn * 64 + ni * 16 + (lane & 15);
        const int off = row * 128 + (kbyte ^ ((row & 7) << 4));
        bfr[ni] = *(const short8*)((const char*)lB + off);
      }
#pragma unroll
      for (int mi = 0; mi < 4; mi++)
#pragma unroll
        for (int ni = 0; ni < 4; ni++)
          acc[mi][ni] = __builtin_amdgcn_mfma_f32_16x16x32_bf16(af[mi], bfr[ni], acc[mi][ni], 0, 0, 0);
    }
  }

  float bcol[4];
#pragma unroll
  for (int ni = 0; ni < 4; ni++)
    bcol[ni] = bias[ntile * 128 + wn * 64 + ni * 16 + (lane & 15)];

#pragma unroll
  for (int mi = 0; mi < 4; mi++) {
#pragma unroll
    for (int j = 0; j < 4; j++) {
      const long crow = mtile * 128 + wm * 64 + mi * 16 + ((lane >> 4) * 4) + j;
#pragma unroll
      for (int ni = 0; ni < 4; ni++) {
        float v = acc[mi][ni][j] + bcol[ni];
        if (GELU) v = gelu_exact(v);
        const long cidx = crow * (long)N + ntile * 128 + wn * 64 + ni * 16 + (lane & 15);
        if (OUT_F32) ((float*)Cout)[cidx] = v;
        else ((unsigned short*)Cout)[cidx] = f2bf(v);
      }
    }
  }
}

extern "C" void kernel_launch(void* const* d_in, const int* in_sizes, int n_in,
                              void* d_out, int out_size, void* d_ws, size_t ws_size,
                              hipStream_t stream) {
  const float* x   = (const float*)d_in[0];
  const int*   sid = (const int*)d_in[1];
  const float* W1  = (const float*)d_in[2];
  const float* b1  = (const float*)d_in[3];
  const float* W2  = (const float*)d_in[4];
  const float* b2  = (const float*)d_in[5];
  const float* Wg1 = (const float*)d_in[6];
  const float* bg1 = (const float*)d_in[7];
  const float* Wg2 = (const float*)d_in[8];
  const float* bg2 = (const float*)d_in[9];
  (void)in_sizes; (void)n_in; (void)out_size; (void)ws_size;

  constexpr int D = 1024, H = 256, S = 4096, B = 4;
  constexpr long NT = (long)B * S;  // 16384 token rows

  char* ws = (char*)d_ws;
  unsigned short* gbuf = (unsigned short*)(ws);
  unsigned short* w1t  = (unsigned short*)(ws + 33554432);
  unsigned short* w2t  = (unsigned short*)(ws + 41943040);
  unsigned short* wg1t = (unsigned short*)(ws + 50331648);
  unsigned short* wg2t = (unsigned short*)(ws + 52428800);
  unsigned short* hbuf = (unsigned short*)(ws + 54525952);
  unsigned short* rout = (unsigned short*)(ws + 62914560);
  int* offs  = (int*)(ws + 96468992);
  int* order = (int*)(ws + 96469248);
  int* tileE = (int*)(ws + 96485632);
  int* tileR = (int*)(ws + 96486208);
  int* ntl   = (int*)(ws + 96486784);
  int* t64E  = (int*)(ws + 96487424);
  int* t64R  = (int*)(ws + 96488704);
  int* ntl64 = (int*)(ws + 96489984);

  route_kernel<<<1, 256, 0, stream>>>(sid, S, offs, order, tileE, tileR, ntl,
                                      t64E, t64R, ntl64);
  prep_kernel<<<dim3(2560), 256, 0, stream>>>(W1, w1t, W2, w2t, Wg1, wg1t, Wg2, wg2t);

  // G1: h = gelu(gather(x,f32) @ W1[e] + b1[e])  [1088 blocks, XCD-colocated]
  gemm_g1g<<<dim3(1088), 256, 0, stream>>>(
      x, w1t, b1, hbuf, order, offs, t64E, t64R, ntl64);
  // G2: rout = h @ W2[e] + b2[e]                 [1152 blocks, XCD-colocated]
  gemm_g2<<<dim3(1152), 256, 0, stream>>>(
      hbuf, w2t, b2, rout, D, H, order, offs, tileE, tileR, ntl, S, (long)D * H, D);
  // GEMM3: g = gelu(rout @ Wg1 + bg1)            [m97 128-tile, 1024 blocks]
  gemm_dense128<true, false><<<dim3((unsigned)(NT / 128) * (D / 128)), 256, 0, stream>>>(
      rout, wg1t, bg1, gbuf, D, D, D / 128);
  // GEMM4: out = g @ Wg2 + bg2                   [fp32 to d_out]
  gemm_dense128<false, true><<<dim3((unsigned)(NT / 128) * (D / 128)), 256, 0, stream>>>(
      gbuf, wg2t, bg2, d_out, D, D, D / 128);
}

// Round 22
// 175.247 us; speedup vs baseline: 1.0302x; 1.0302x over previous
//
#include <hip/hip_runtime.h>

// SplatAwareFeedForward on MI355X (gfx950).
// Pipeline: route -> prep (weight transposes ONLY) ->
//           G1 (fused gather+cast f32 x, 64x64 tiles, BK=128, XCD-colocated) ->
//           G2 (m97-style, r19 grid) -> dense GEMM3/GEMM4 (m97 128x128, XCD swizzle).
// r21 lesson: G2 XCD-colocation null (L3 already absorbs hbuf re-reads) -> reverted.
// This round: G1 BK 64->128 halves the barrier count (16->8 K-steps); G1 pays 32
// gather-latency drains at BK=64 and is neither HBM- nor MFMA-bound.
// Workspace layout (bytes):
//   gbuf  @ 0        : 33,554,432  (dense g-buffer GEMM3 out / GEMM4 in)
//   w1t   @ 33554432 :  8,388,608  (E*[H][D] bf16, transposed W1)
//   w2t   @ 41943040 :  8,388,608  (E*[D][H] bf16, transposed W2)
//   wg1t  @ 50331648 :  2,097,152  ([D][D] bf16, transposed Wg1)
//   wg2t  @ 52428800 :  2,097,152  ([D][D] bf16, transposed Wg2)
//   hbuf  @ 54525952 :  8,388,608  (B*S*H bf16, expert-sorted hidden)
//   rout  @ 62914560 : 33,554,432  (B*S*D bf16, routed output, natural order)
//   offs  @ 96468992 : 68          (E+1 ints)
//   order @ 96469248 : 16,384      (S ints sorted by expert)
//   tileE @ 96485632 : 576         (expert id per 128-row tile, <=144)
//   tileR @ 96486208 : 576         (sorted-row start per 128-row tile)
//   ntl   @ 96486784 : 4           (128-row tile count)
//   t64E  @ 96487424 : 1,152       (expert id per 64-row tile, <=272)
//   t64R  @ 96488704 : 1,152       (sorted-row start per 64-row tile)
//   ntl64 @ 96489984 : 4           (64-row tile count)

#define DEV __device__ __forceinline__

typedef float f32x4 __attribute__((ext_vector_type(4)));
typedef short short8 __attribute__((ext_vector_type(8)));

DEV unsigned short f2bf(float f) {
  unsigned u = __float_as_uint(f);
  u += 0x7fffu + ((u >> 16) & 1u);   // round-to-nearest-even
  return (unsigned short)(u >> 16);
}

DEV void gload16(const void* g, void* l) {
  __builtin_amdgcn_global_load_lds(
      (const __attribute__((address_space(1))) unsigned int*)g,
      (__attribute__((address_space(3))) unsigned int*)l, 16, 0, 0);
}

DEV float gelu_exact(float v) {
  return 0.5f * v * (1.0f + erff(v * 0.70710678118654752f));
}

// ---------------- routing: sorted order + 128-row and 64-row tile lists ----------------
__global__ __launch_bounds__(256) void route_kernel(
    const int* __restrict__ sid, int S, int* __restrict__ offs, int* __restrict__ order,
    int* __restrict__ tileE, int* __restrict__ tileR, int* __restrict__ ntl,
    int* __restrict__ t64E, int* __restrict__ t64R, int* __restrict__ ntl64) {
  __shared__ int cnt[16], cur[16];
  const int t = threadIdx.x;
  if (t < 16) cnt[t] = 0;
  __syncthreads();
  for (int s = t; s < S; s += 256) atomicAdd(&cnt[sid[s]], 1);
  __syncthreads();
  if (t == 0) {
    int a = 0;
    for (int e = 0; e < 16; e++) { offs[e] = a; cur[e] = a; a += cnt[e]; }
    offs[16] = a;
    int nt = 0, n64 = 0;
    for (int e = 0; e < 16; e++) {
      const int rows = 4 * cnt[e];
      for (int r = 0; r < rows; r += 128) {
        tileE[nt] = e; tileR[nt] = 4 * offs[e] + r; nt++;
      }
      for (int r = 0; r < rows; r += 64) {
        t64E[n64] = e; t64R[n64] = 4 * offs[e] + r; n64++;
      }
    }
    ntl[0] = nt;
    ntl64[0] = n64;
  }
  __syncthreads();
  for (int s = t; s < S; s += 256) {
    int p = atomicAdd(&cur[sid[s]], 1);
    order[p] = s;
  }
}

// ---------------- prep: weight transpose-casts ONLY ----------------
__global__ __launch_bounds__(256) void prep_kernel(
    const float* __restrict__ W1, unsigned short* __restrict__ w1t,
    const float* __restrict__ W2, unsigned short* __restrict__ w2t,
    const float* __restrict__ Wg1, unsigned short* __restrict__ wg1t,
    const float* __restrict__ Wg2, unsigned short* __restrict__ wg2t) {
  __shared__ float tile[64][65];
  const int t = threadIdx.x;
  int id = (int)blockIdx.x;
  const float* in; unsigned short* out;
  int R, C, r0, c0; long base;
  if (id < 1024) {          // W1: [1024][256] -> [256][1024] per expert
    in = W1; out = w1t; R = 1024; C = 256;
    base = (long)(id >> 6) * 262144;
    r0 = ((id >> 2) & 15) * 64; c0 = (id & 3) * 64;
  } else if (id < 2048) {   // W2: [256][1024] -> [1024][256] per expert
    id -= 1024;
    in = W2; out = w2t; R = 256; C = 1024;
    base = (long)(id >> 6) * 262144;
    r0 = ((id >> 4) & 3) * 64; c0 = (id & 15) * 64;
  } else if (id < 2304) {   // Wg1
    id -= 2048;
    in = Wg1; out = wg1t; R = 1024; C = 1024; base = 0;
    r0 = (id >> 4) * 64; c0 = (id & 15) * 64;
  } else {                  // Wg2
    id -= 2304;
    in = Wg2; out = wg2t; R = 1024; C = 1024; base = 0;
    r0 = (id >> 4) * 64; c0 = (id & 15) * 64;
  }
  const int cc = t & 63, rr = t >> 6;
#pragma unroll
  for (int i = 0; i < 16; i++) {
    int r = rr + i * 4;
    tile[r][cc] = in[base + (long)(r0 + r) * C + (c0 + cc)];
  }
  __syncthreads();
#pragma unroll
  for (int i = 0; i < 16; i++) {
    int c = rr + i * 4;
    out[base + (long)(c0 + c) * R + (r0 + cc)] = f2bf(tile[cc][c]);
  }
}

// ---------------- G1: h = gelu(gather(x,f32) @ W1[e] + b1[e]), 64x64 tiles, BK=128 ----------------
// Linear 1088-block grid, XCD-colocated ntile siblings (r19 decode). 8 K-steps of
// 128 (half the barriers of BK=64). A: f32 gather via order[], cast in regs,
// ds_write to linear dst with pre-swizzled source column (byte ^= (row&7)<<4 within
// 256B rows). B via gload16, same swizzle. LDS 32KB -> 4 blocks/CU (VGPR ~60).
__global__ __launch_bounds__(256, 4) void gemm_g1g(
    const float* __restrict__ x,
    const unsigned short* __restrict__ w1t, const float* __restrict__ b1,
    unsigned short* __restrict__ hbuf,
    const int* __restrict__ order, const int* __restrict__ offs,
    const int* __restrict__ t64E, const int* __restrict__ t64R,
    const int* __restrict__ ntl64) {
  constexpr int S = 4096, D = 1024, H = 256;
  const int b = (int)blockIdx.x;
  const int xcd = b & 7;
  const int q = b >> 3;
  const int ntile = q & 3;                 // 0..3 (64-col block of H)
  const int ti = (q >> 2) * 8 + xcd;       // 0..271 (64-row tile)
  if (ti >= ntl64[0]) return;
  const int t = (int)threadIdx.x;
  const int lane = t & 63;
  const int w = t >> 6;
  const int wm = w >> 1, wn = w & 1;       // 2x2 waves, 32x32 each

  const int e = t64E[ti];
  const int rowBase = t64R[ti];
  int Me = 4 * offs[e + 1] - rowBase;
  if (Me > 64) Me = 64;

  __shared__ __align__(16) unsigned short lA[64 * 128];   // 16KB (x tile, bf16, swizzled)
  __shared__ __align__(16) unsigned short lB[64 * 128];   // 16KB (W1 slab)

  // A gather: 4 groups x 16 rows; thread -> row = i*16 + (t>>4), slot = t&15.
  // LDS dst linear: row*128 + slot*8 (bf16 elems); source col pre-swizzled.
  const float* xsrc[4];
  int aDst[4];
#pragma unroll
  for (int i = 0; i < 4; i++) {
    const int row = i * 16 + (t >> 4);
    const int bOff = ((t & 15) * 16) ^ ((row & 7) << 4);   // byte within 256B row
    const int rr = (row < Me) ? row : (Me - 1);
    const int g = rowBase + rr;
    xsrc[i] = x + ((long)(g & 3) * S + order[g >> 2]) * D + (bOff >> 1);
    aDst[i] = row * 128 + (t & 15) * 8;
  }
  // B: w1t[e] is [H=256][D=1024]; slab rows ntile*64..+64, 4 issues x 16 rows.
  const unsigned short* bSrc[4];
#pragma unroll
  for (int i = 0; i < 4; i++) {
    const int row = i * 16 + (t >> 4);
    bSrc[i] = w1t + (long)e * H * D + (long)(ntile * 64 + row) * D +
              ((((t & 15) * 16) ^ ((row & 7) << 4)) >> 1);
  }
  const int dstE = (t >> 4) * 128 + (t & 15) * 8;          // = wave-base + lane*16B

  f32x4 acc[2][2] = {};
  float4 xv[4][2];
#pragma unroll
  for (int i = 0; i < 4; i++) {
    xv[i][0] = *(const float4*)(xsrc[i]);
    xv[i][1] = *(const float4*)(xsrc[i] + 4);
  }

  for (int kt = 0; kt < 8; kt++) {
    __syncthreads();                   // prev compute done reading lA/lB
#pragma unroll
    for (int i = 0; i < 4; i++) {
      short8 av;
      av[0] = (short)f2bf(xv[i][0].x); av[1] = (short)f2bf(xv[i][0].y);
      av[2] = (short)f2bf(xv[i][0].z); av[3] = (short)f2bf(xv[i][0].w);
      av[4] = (short)f2bf(xv[i][1].x); av[5] = (short)f2bf(xv[i][1].y);
      av[6] = (short)f2bf(xv[i][1].z); av[7] = (short)f2bf(xv[i][1].w);
      *(short8*)(lA + aDst[i]) = av;
      gload16(bSrc[i] + (kt << 7), lB + i * 2048 + dstE);
    }
    if (kt < 7) {
#pragma unroll
      for (int i = 0; i < 4; i++) {
        xv[i][0] = *(const float4*)(xsrc[i] + (kt + 1) * 128);
        xv[i][1] = *(const float4*)(xsrc[i] + (kt + 1) * 128 + 4);
      }
    }
    __syncthreads();                   // lA written + lB staged
#pragma unroll
    for (int kk = 0; kk < 4; kk++) {
      short8 aF[2], bF[2];
      const int kb = kk * 64 + ((lane >> 4) << 4);         // byte in 256B row
#pragma unroll
      for (int mi = 0; mi < 2; mi++) {
        const int row = wm * 32 + mi * 16 + (lane & 15);
        aF[mi] = *(const short8*)((const char*)lA + row * 256 + (kb ^ ((row & 7) << 4)));
      }
#pragma unroll
      for (int ni = 0; ni < 2; ni++) {
        const int row = wn * 32 + ni * 16 + (lane & 15);
        bF[ni] = *(const short8*)((const char*)lB + row * 256 + (kb ^ ((row & 7) << 4)));
      }
#pragma unroll
      for (int mi = 0; mi < 2; mi++)
#pragma unroll
        for (int ni = 0; ni < 2; ni++)
          acc[mi][ni] = __builtin_amdgcn_mfma_f32_16x16x32_bf16(aF[mi], bF[ni], acc[mi][ni], 0, 0, 0);
    }
  }

  float bc[2];
#pragma unroll
  for (int ni = 0; ni < 2; ni++)
    bc[ni] = b1[e * H + ntile * 64 + wn * 32 + ni * 16 + (lane & 15)];
#pragma unroll
  for (int mi = 0; mi < 2; mi++)
#pragma unroll
    for (int j = 0; j < 4; j++) {
      const int lrow = wm * 32 + mi * 16 + ((lane >> 4) << 2) + j;
      if (lrow >= Me) continue;
      const long crow = rowBase + lrow;
#pragma unroll
      for (int ni = 0; ni < 2; ni++) {
        const float v = gelu_exact(acc[mi][ni][j] + bc[ni]);
        hbuf[crow * H + ntile * 64 + wn * 32 + ni * 16 + (lane & 15)] = f2bf(v);
      }
    }
}

// ---------------- G2: expert 128x128x64 (m97-style, r19 grid) ----------------
__global__ __launch_bounds__(256, 4) void gemm_g2(
    const unsigned short* __restrict__ A, const unsigned short* __restrict__ BT,
    const float* __restrict__ bias, unsigned short* __restrict__ Cout,
    int N, int K,
    const int* __restrict__ order, const int* __restrict__ offs,
    const int* __restrict__ tileE, const int* __restrict__ tileR,
    const int* __restrict__ ntl,
    int S, long btStride, int biasStride) {
  const int ti = (int)blockIdx.y;
  if (ti >= ntl[0]) return;
  const int t = (int)threadIdx.x;
  const int lane = t & 63;
  const int w = t >> 6;
  const int wm = w >> 1, wn = w & 1;
  const int tileN = (int)blockIdx.x;

  const int e = tileE[ti];
  const int rowBase = tileR[ti];
  int Me = 4 * offs[e + 1] - rowBase;
  if (Me > 128) Me = 128;
  const unsigned short* bt = BT + (long)e * btStride;
  const float* bs = bias + (long)e * biasStride;

  __shared__ __align__(16) unsigned short lA[128 * 64];
  __shared__ __align__(16) unsigned short lB[128 * 64];

  const unsigned short* aSrc[4];
  const unsigned short* bSrc[4];
  {
    const int qq = t & 7;
#pragma unroll
    for (int i = 0; i < 4; i++) {
      const int row = i * 32 + (t >> 3);
      const int koff = ((qq * 16) ^ ((row & 7) << 4)) >> 1;
      const int rr = (row < Me) ? row : (Me - 1);
      aSrc[i] = A + (long)(rowBase + rr) * K + koff;
      const int col = tileN * 128 + row;
      bSrc[i] = bt + (long)col * K + koff;
    }
  }

  f32x4 acc[4][4] = {};

  const int KT = K >> 6;
  for (int kt = 0; kt < KT; kt++) {
    __syncthreads();
#pragma unroll
    for (int i = 0; i < 4; i++) {
      gload16(aSrc[i] + (kt << 6), (void*)(lA + i * 2048 + w * 512));
      gload16(bSrc[i] + (kt << 6), (void*)(lB + i * 2048 + w * 512));
    }
    __syncthreads();
#pragma unroll
    for (int kk = 0; kk < 2; kk++) {
      short8 af[4], bfr[4];
      const int kbyte = kk * 64 + (lane >> 4) * 16;
#pragma unroll
      for (int mi = 0; mi < 4; mi++) {
        const int row = wm * 64 + mi * 16 + (lane & 15);
        const int off = row * 128 + (kbyte ^ ((row & 7) << 4));
        af[mi] = *(const short8*)((const char*)lA + off);
      }
#pragma unroll
      for (int ni = 0; ni < 4; ni++) {
        const int row = wn * 64 + ni * 16 + (lane & 15);
        const int off = row * 128 + (kbyte ^ ((row & 7) << 4));
        bfr[ni] = *(const short8*)((const char*)lB + off);
      }
#pragma unroll
      for (int mi = 0; mi < 4; mi++)
#pragma unroll
        for (int ni = 0; ni < 4; ni++)
          acc[mi][ni] = __builtin_amdgcn_mfma_f32_16x16x32_bf16(af[mi], bfr[ni], acc[mi][ni], 0, 0, 0);
    }
  }

  float bcol[4];
#pragma unroll
  for (int ni = 0; ni < 4; ni++)
    bcol[ni] = bs[tileN * 128 + wn * 64 + ni * 16 + (lane & 15)];

#pragma unroll
  for (int mi = 0; mi < 4; mi++) {
#pragma unroll
    for (int j = 0; j < 4; j++) {
      const int lrow = wm * 64 + mi * 16 + ((lane >> 4) * 4) + j;
      if (lrow >= Me) continue;
      const int g = rowBase + lrow;
      const long crow = (long)(g & 3) * S + order[g >> 2];   // scatter to natural rows
#pragma unroll
      for (int ni = 0; ni < 4; ni++) {
        const float v = acc[mi][ni][j] + bcol[ni];
        Cout[crow * (long)N + tileN * 128 + wn * 64 + ni * 16 + (lane & 15)] = f2bf(v);
      }
    }
  }
}

// ---------------- dense 128x128x64 GEMM (m97 structure, 4 blocks/CU, XCD swizzle) ----------------
template <bool GELU, bool OUT_F32>
__global__ __launch_bounds__(256, 4) void gemm_dense128(
    const unsigned short* __restrict__ A, const unsigned short* __restrict__ BT,
    const float* __restrict__ bias, void* __restrict__ Cout,
    int N, int K, int ntiles) {
  const int t = (int)threadIdx.x;
  const int lane = t & 63;
  const int w = t >> 6;
  const int wm = w >> 1, wn = w & 1;

  const int cpx = (int)gridDim.x >> 3;
  const int swz = ((int)blockIdx.x & 7) * cpx + ((int)blockIdx.x >> 3);
  const int mtile = swz / ntiles, ntile = swz % ntiles;

  __shared__ __align__(16) unsigned short lA[128 * 64];
  __shared__ __align__(16) unsigned short lB[128 * 64];

  const unsigned short* aSrc[4];
  const unsigned short* bSrc[4];
  {
    const int q = t & 7;
#pragma unroll
    for (int i = 0; i < 4; i++) {
      const int row = i * 32 + (t >> 3);
      const int koff = ((q * 16) ^ ((row & 7) << 4)) >> 1;
      aSrc[i] = A + (long)(mtile * 128 + row) * K + koff;
      bSrc[i] = BT + (long)(ntile * 128 + row) * K + koff;
    }
  }

  f32x4 acc[4][4] = {};

  const int KT = K >> 6;
  for (int kt = 0; kt < KT; kt++) {
    __syncthreads();
#pragma unroll
    for (int i = 0; i < 4; i++) {
      gload16(aSrc[i] + (kt << 6), (void*)(lA + i * 2048 + w * 512));
      gload16(bSrc[i] + (kt << 6), (void*)(lB + i * 2048 + w * 512));
    }
    __syncthreads();
#pragma unroll
    for (int kk = 0; kk < 2; kk++) {
      short8 af[4], bfr[4];
      const int kbyte = kk * 64 + (lane >> 4) * 16;
#pragma unroll
      for (int mi = 0; mi < 4; mi++) {
        const int row = wm * 64 + mi * 16 + (lane & 15);
        const int off = row * 128 + (kbyte ^ ((row & 7) << 4));
        af[mi] = *(const short8*)((const char*)lA + off);
      }
#pragma unroll
      for (int ni = 0; ni < 4; ni++) {
        const int row = wn * 64 + ni * 16 + (lane & 15);
        const int off = row * 128 + (kbyte ^ ((row & 7) << 4));
        bfr[ni] = *(const short8*)((const char*)lB + off);
      }
#pragma unroll
      for (int mi = 0; mi < 4; mi++)
#pragma unroll
        for (int ni = 0; ni < 4; ni++)
          acc[mi][ni] = __builtin_amdgcn_mfma_f32_16x16x32_bf16(af[mi], bfr[ni], acc[mi][ni], 0, 0, 0);
    }
  }

  float bcol[4];
#pragma unroll
  for (int ni = 0; ni < 4; ni++)
    bcol[ni] = bias[ntile * 128 + wn * 64 + ni * 16 + (lane & 15)];

#pragma unroll
  for (int mi = 0; mi < 4; mi++) {
#pragma unroll
    for (int j = 0; j < 4; j++) {
      const long crow = mtile * 128 + wm * 64 + mi * 16 + ((lane >> 4) * 4) + j;
#pragma unroll
      for (int ni = 0; ni < 4; ni++) {
        float v = acc[mi][ni][j] + bcol[ni];
        if (GELU) v = gelu_exact(v);
        const long cidx = crow * (long)N + ntile * 128 + wn * 64 + ni * 16 + (lane & 15);
        if (OUT_F32) ((float*)Cout)[cidx] = v;
        else ((unsigned short*)Cout)[cidx] = f2bf(v);
      }
    }
  }
}

extern "C" void kernel_launch(void* const* d_in, const int* in_sizes, int n_in,
                              void* d_out, int out_size, void* d_ws, size_t ws_size,
                              hipStream_t stream) {
  const float* x   = (const float*)d_in[0];
  const int*   sid = (const int*)d_in[1];
  const float* W1  = (const float*)d_in[2];
  const float* b1  = (const float*)d_in[3];
  const float* W2  = (const float*)d_in[4];
  const float* b2  = (const float*)d_in[5];
  const float* Wg1 = (const float*)d_in[6];
  const float* bg1 = (const float*)d_in[7];
  const float* Wg2 = (const float*)d_in[8];
  const float* bg2 = (const float*)d_in[9];
  (void)in_sizes; (void)n_in; (void)out_size; (void)ws_size;

  constexpr int D = 1024, H = 256, S = 4096, B = 4;
  constexpr long NT = (long)B * S;  // 16384 token rows

  char* ws = (char*)d_ws;
  unsigned short* gbuf = (unsigned short*)(ws);
  unsigned short* w1t  = (unsigned short*)(ws + 33554432);
  unsigned short* w2t  = (unsigned short*)(ws + 41943040);
  unsigned short* wg1t = (unsigned short*)(ws + 50331648);
  unsigned short* wg2t = (unsigned short*)(ws + 52428800);
  unsigned short* hbuf = (unsigned short*)(ws + 54525952);
  unsigned short* rout = (unsigned short*)(ws + 62914560);
  int* offs  = (int*)(ws + 96468992);
  int* order = (int*)(ws + 96469248);
  int* tileE = (int*)(ws + 96485632);
  int* tileR = (int*)(ws + 96486208);
  int* ntl   = (int*)(ws + 96486784);
  int* t64E  = (int*)(ws + 96487424);
  int* t64R  = (int*)(ws + 96488704);
  int* ntl64 = (int*)(ws + 96489984);

  route_kernel<<<1, 256, 0, stream>>>(sid, S, offs, order, tileE, tileR, ntl,
                                      t64E, t64R, ntl64);
  prep_kernel<<<dim3(2560), 256, 0, stream>>>(W1, w1t, W2, w2t, Wg1, wg1t, Wg2, wg2t);

  // G1: h = gelu(gather(x,f32) @ W1[e] + b1[e])  [1088 blocks, BK=128, XCD-colocated]
  gemm_g1g<<<dim3(1088), 256, 0, stream>>>(
      x, w1t, b1, hbuf, order, offs, t64E, t64R, ntl64);
  // G2: rout = h @ W2[e] + b2[e]                 [r19 grid, scatter to natural rows]
  gemm_g2<<<dim3(D / 128, 144), 256, 0, stream>>>(
      hbuf, w2t, b2, rout, D, H, order, offs, tileE, tileR, ntl, S, (long)D * H, D);
  // GEMM3: g = gelu(rout @ Wg1 + bg1)            [m97 128-tile, 1024 blocks]
  gemm_dense128<true, false><<<dim3((unsigned)(NT / 128) * (D / 128)), 256, 0, stream>>>(
      rout, wg1t, bg1, gbuf, D, D, D / 128);
  // GEMM4: out = g @ Wg2 + bg2                   [fp32 to d_out]
  gemm_dense128<false, true><<<dim3((unsigned)(NT / 128) * (D / 128)), 256, 0, stream>>>(
      gbuf, wg2t, bg2, d_out, D, D, D / 128);
}